// Round 1
// baseline (805.190 us; speedup 1.0000x reference)
//
#include <hip/hip_runtime.h>

// UnigramLM forward-backward posterior, T=2048, L=8, V=32000.
// Kernel A: block 0 = forward alpha scan, block 1 = backward beta scan,
//           blocks 2.. = zero-fill of the 262MB output (all concurrent).
// Kernel B: scatter exp(alpha[t] + w + beta[t+l] - alpha[T]) into P[t, idx].

#define NEGV -1e9f
constexpr int T = 2048;
constexpr int L = 8;
constexpr int V = 32000;
constexpr int FILL_BLOCKS = 2048;

__device__ __forceinline__ float lse8(const float* t) {
    float m = fmaxf(fmaxf(fmaxf(t[0], t[1]), fmaxf(t[2], t[3])),
                    fmaxf(fmaxf(t[4], t[5]), fmaxf(t[6], t[7])));
    float s = __expf(t[0] - m) + __expf(t[1] - m) + __expf(t[2] - m) + __expf(t[3] - m)
            + __expf(t[4] - m) + __expf(t[5] - m) + __expf(t[6] - m) + __expf(t[7] - m);
    return m + __logf(s);
}

__global__ __launch_bounds__(256) void scan_fill_kernel(
        const float* __restrict__ logp, const int* __restrict__ midx,
        float* __restrict__ out, float* __restrict__ alpha, float* __restrict__ beta) {
    __shared__ float s[T * L];  // 64 KB
    const int tid = threadIdx.x;

    if (blockIdx.x == 0) {
        // ---- forward scan: needs wrev[r][j] = w[r-j][j] (NEG where r<j) ----
        for (int i = tid; i < T * L; i += 256) s[i] = NEGV;
        __syncthreads();
        for (int i = tid; i < T * L; i += 256) {
            int m = midx[i];
            if (m >= 0) {
                int t = i >> 3, j = i & 7;
                int r = t + j;
                if (r < T) s[r * L + j] = logp[m];
            }
        }
        __syncthreads();
        if (tid == 0) {
            float ab[L];  // ab[j] = alpha[n-1-j]
            ab[0] = 0.f;
#pragma unroll
            for (int j = 1; j < L; ++j) ab[j] = NEGV;
            alpha[0] = 0.f;
            // distance-2 prefetch of LDS rows to hide ds_read latency
            float cur[L], n1[L], n2[L];
#pragma unroll
            for (int j = 0; j < L; ++j) cur[j] = s[0 * L + j];
#pragma unroll
            for (int j = 0; j < L; ++j) n1[j] = s[1 * L + j];
            for (int n = 1; n <= T; ++n) {
                if (n + 1 <= T - 1) {
#pragma unroll
                    for (int j = 0; j < L; ++j) n2[j] = s[(n + 1) * L + j];
                }
                float tm[L];
#pragma unroll
                for (int j = 0; j < L; ++j) tm[j] = cur[j] + ab[j];
                float a = lse8(tm);
                alpha[n] = a;
#pragma unroll
                for (int j = L - 1; j > 0; --j) ab[j] = ab[j - 1];
                ab[0] = a;
#pragma unroll
                for (int j = 0; j < L; ++j) { cur[j] = n1[j]; n1[j] = n2[j]; }
            }
        }
    } else if (blockIdx.x == 1) {
        // ---- backward scan: uses w rows directly ----
        for (int i = tid; i < T * L; i += 256) {
            int m = midx[i];
            s[i] = (m >= 0) ? logp[m] : NEGV;
        }
        __syncthreads();
        if (tid == 0) {
            float bb[L];  // bb[j] = beta[t+1+j]
            bb[0] = 0.f;
#pragma unroll
            for (int j = 1; j < L; ++j) bb[j] = NEGV;
            beta[T] = 0.f;
            float cur[L], n1[L], n2[L];
#pragma unroll
            for (int j = 0; j < L; ++j) cur[j] = s[(T - 1) * L + j];
#pragma unroll
            for (int j = 0; j < L; ++j) n1[j] = s[(T - 2) * L + j];
            for (int t = T - 1; t >= 0; --t) {
                if (t - 2 >= 0) {
#pragma unroll
                    for (int j = 0; j < L; ++j) n2[j] = s[(t - 2) * L + j];
                }
                float tm[L];
#pragma unroll
                for (int j = 0; j < L; ++j) tm[j] = cur[j] + bb[j];
                float b = lse8(tm);
                beta[t] = b;
#pragma unroll
                for (int j = L - 1; j > 0; --j) bb[j] = bb[j - 1];
                bb[0] = b;
#pragma unroll
                for (int j = 0; j < L; ++j) { cur[j] = n1[j]; n1[j] = n2[j]; }
            }
        }
    } else {
        // ---- zero-fill the output ----
        float4 z = make_float4(0.f, 0.f, 0.f, 0.f);
        float4* o4 = (float4*)out;
        const size_t n4 = (size_t)T * V / 4;
        size_t i = (size_t)(blockIdx.x - 2) * blockDim.x + tid;
        const size_t stride = (size_t)(gridDim.x - 2) * blockDim.x;
        for (; i < n4; i += stride) o4[i] = z;
    }
}

__global__ __launch_bounds__(256) void scatter_kernel(
        const float* __restrict__ logp, const int* __restrict__ midx,
        float* __restrict__ out, const float* __restrict__ alpha,
        const float* __restrict__ beta) {
    int i = blockIdx.x * blockDim.x + threadIdx.x;
    if (i >= T * L) return;
    int m = midx[i];
    if (m < 0) return;
    int t = i >> 3, j = i & 7;
    int nx = t + j + 1;
    if (nx > T) nx = T;
    float lp = alpha[t] + logp[m] + beta[nx] - alpha[T];
    atomicAdd(&out[(size_t)t * V + m], __expf(lp));
}

extern "C" void kernel_launch(void* const* d_in, const int* in_sizes, int n_in,
                              void* d_out, int out_size, void* d_ws, size_t ws_size,
                              hipStream_t stream) {
    const float* logp = (const float*)d_in[0];   // [V]
    const int*   midx = (const int*)d_in[1];     // [T, L]
    float* out = (float*)d_out;                  // [T, V]
    float* alpha = (float*)d_ws;                 // [T+1]
    float* beta  = alpha + (T + 1);              // [T+1]

    scan_fill_kernel<<<dim3(2 + FILL_BLOCKS), 256, 0, stream>>>(logp, midx, out, alpha, beta);
    scatter_kernel<<<dim3((T * L) / 256), 256, 0, stream>>>(logp, midx, out, alpha, beta);
}

// Round 2
// 340.958 us; speedup vs baseline: 2.3616x; 2.3616x over previous
//
#include <hip/hip_runtime.h>

// UnigramLM forward-backward posterior, T=2048, L=8, V=32000.
// R2: chunked log-semiring parallel scan (32 chunks x 64 steps).
//   Kernel A: block 0 = forward alpha scan, block 1 = backward beta scan,
//             blocks 2.. = 262MB zero-fill (all concurrent; no LDS anywhere
//             so fill occupancy is not LDS-capped).
//   Kernel B: scatter exp(alpha[t] + w + beta[t+l] - alpha[T]) into P[t, idx].

#define NEGV -1e9f
constexpr int T = 2048;
constexpr int L = 8;
constexpr int V = 32000;
constexpr int NCH = 32;   // chunks per scan
constexpr int K = 64;     // steps per chunk (NCH*K == T)
constexpr int GRID = 2048;

__device__ __forceinline__ float lse8v(float t0, float t1, float t2, float t3,
                                       float t4, float t5, float t6, float t7) {
    float m = fmaxf(fmaxf(fmaxf(t0, t1), fmaxf(t2, t3)),
                    fmaxf(fmaxf(t4, t5), fmaxf(t6, t7)));
    float s = __expf(t0 - m) + __expf(t1 - m) + __expf(t2 - m) + __expf(t3 - m)
            + __expf(t4 - m) + __expf(t5 - m) + __expf(t6 - m) + __expf(t7 - m);
    return m + __logf(s);
}

// Chunked scan over staged rows w[T][8] (row r consumed at step r).
// Companion-matrix semantics: top = lse8(w_row[j] + state[j]); shift; state[0]=top.
// Pm: [NCH][8][8] scratch, vst: [(NCH+1)*8] boundary states, outv: emit target.
// backward=false: emit outv[s+1]; backward=true: emit outv[T-1-s].
__device__ void chunked_scan(const float* __restrict__ w, float* __restrict__ Pm,
                             float* __restrict__ vst, float* __restrict__ outv,
                             bool backward) {
    const int tid = threadIdx.x;

    // ---- phase 1: per-chunk operator composition; thread (c,col) owns column col
    {
        const int c = tid >> 3, col = tid & 7;
        float q[8];
#pragma unroll
        for (int i = 0; i < 8; ++i) q[i] = (i == col) ? 0.f : NEGV;
        const float4* wr4 = (const float4*)(w + c * K * 8);
        float4 c0 = wr4[0], c1 = wr4[1];
        float4 b0 = wr4[2], b1 = wr4[3];
        for (int k = 0; k < K; ++k) {
            float4 a0, a1;
            if (k + 2 < K) { a0 = wr4[(k + 2) * 2]; a1 = wr4[(k + 2) * 2 + 1]; }
            float top = lse8v(c0.x + q[0], c0.y + q[1], c0.z + q[2], c0.w + q[3],
                              c1.x + q[4], c1.y + q[5], c1.z + q[6], c1.w + q[7]);
#pragma unroll
            for (int i = 7; i > 0; --i) q[i] = q[i - 1];
            q[0] = top;
            c0 = b0; c1 = b1; b0 = a0; b1 = a1;
        }
#pragma unroll
        for (int i = 0; i < 8; ++i) Pm[c * 64 + i * 8 + col] = q[i];
    }
    __syncthreads();

    // ---- phase 2: sequential combine across chunks (lanes 0..7 of wave 0)
    if (tid < 8) {
        const int r = tid;
        float v = (r == 0) ? 0.f : NEGV;
        float4 r0 = ((const float4*)(Pm + r * 8))[0];
        float4 r1 = ((const float4*)(Pm + r * 8))[1];
        for (int cc = 0; cc < NCH; ++cc) {
            vst[cc * 8 + r] = v;
            float4 n0, n1;
            if (cc + 1 < NCH) {
                n0 = ((const float4*)(Pm + (cc + 1) * 64 + r * 8))[0];
                n1 = ((const float4*)(Pm + (cc + 1) * 64 + r * 8))[1];
            }
            float vb0 = __shfl(v, 0, 8), vb1 = __shfl(v, 1, 8);
            float vb2 = __shfl(v, 2, 8), vb3 = __shfl(v, 3, 8);
            float vb4 = __shfl(v, 4, 8), vb5 = __shfl(v, 5, 8);
            float vb6 = __shfl(v, 6, 8), vb7 = __shfl(v, 7, 8);
            v = lse8v(r0.x + vb0, r0.y + vb1, r0.z + vb2, r0.w + vb3,
                      r1.x + vb4, r1.y + vb5, r1.z + vb6, r1.w + vb7);
            r0 = n0; r1 = n1;
        }
        vst[NCH * 8 + r] = v;
    }
    __syncthreads();

    // ---- phase 3: re-run each chunk from its boundary state, emitting values
    if (tid < NCH) {
        const int cc = tid;
        float ab[8];
#pragma unroll
        for (int i = 0; i < 8; ++i) ab[i] = vst[cc * 8 + i];
        const float4* wr4 = (const float4*)(w + cc * K * 8);
        float4 c0 = wr4[0], c1 = wr4[1];
        float4 b0 = wr4[2], b1 = wr4[3];
        for (int k = 0; k < K; ++k) {
            float4 a0, a1;
            if (k + 2 < K) { a0 = wr4[(k + 2) * 2]; a1 = wr4[(k + 2) * 2 + 1]; }
            float val = lse8v(c0.x + ab[0], c0.y + ab[1], c0.z + ab[2], c0.w + ab[3],
                              c1.x + ab[4], c1.y + ab[5], c1.z + ab[6], c1.w + ab[7]);
            int s = cc * K + k;
            if (!backward) outv[s + 1] = val;
            else           outv[T - 1 - s] = val;
#pragma unroll
            for (int i = 7; i > 0; --i) ab[i] = ab[i - 1];
            ab[0] = val;
            c0 = b0; c1 = b1; b0 = a0; b1 = a1;
        }
    }
}

__global__ __launch_bounds__(256) void scan_fill_kernel(
        const float* __restrict__ logp, const int* __restrict__ midx,
        float* __restrict__ out, float* __restrict__ alpha, float* __restrict__ beta,
        float* __restrict__ wf, float* __restrict__ wb,
        float* __restrict__ Pmf, float* __restrict__ Pmb,
        float* __restrict__ vstf, float* __restrict__ vstb) {
    const int tid = threadIdx.x;

    if (blockIdx.x == 0) {
        // stage wrev: wf[r][j] = w[r-j][j] (NEG if r<j or no match)
        for (int o = tid; o < T * L; o += 256) {
            int r = o >> 3, j = o & 7, t = r - j;
            float v = NEGV;
            if (t >= 0) { int m = midx[t * 8 + j]; if (m >= 0) v = logp[m]; }
            wf[o] = v;
        }
        if (tid == 0) alpha[0] = 0.f;
        __syncthreads();
        chunked_scan(wf, Pmf, vstf, alpha, false);
    } else if (blockIdx.x == 1) {
        // stage reversed rows: wb[s][j] = w[T-1-s][j]
        for (int o = tid; o < T * L; o += 256) {
            int s = o >> 3, j = o & 7, t = T - 1 - s;
            int m = midx[t * 8 + j];
            wb[o] = (m >= 0) ? logp[m] : NEGV;
        }
        if (tid == 0) beta[T] = 0.f;
        __syncthreads();
        chunked_scan(wb, Pmb, vstb, beta, true);
    } else {
        float4 z = make_float4(0.f, 0.f, 0.f, 0.f);
        float4* o4 = (float4*)out;
        const size_t n4 = (size_t)T * V / 4;
        size_t i = (size_t)(blockIdx.x - 2) * blockDim.x + tid;
        const size_t stride = (size_t)(GRID - 2) * blockDim.x;
        for (; i < n4; i += stride) o4[i] = z;
    }
}

__global__ __launch_bounds__(256) void scatter_kernel(
        const float* __restrict__ logp, const int* __restrict__ midx,
        float* __restrict__ out, const float* __restrict__ alpha,
        const float* __restrict__ beta) {
    int i = blockIdx.x * blockDim.x + threadIdx.x;
    if (i >= T * L) return;
    int m = midx[i];
    if (m < 0) return;
    int t = i >> 3, j = i & 7;
    int nx = t + j + 1;
    if (nx > T) nx = T;
    float lp = alpha[t] + logp[m] + beta[nx] - alpha[T];
    atomicAdd(&out[(size_t)t * V + m], __expf(lp));
}

extern "C" void kernel_launch(void* const* d_in, const int* in_sizes, int n_in,
                              void* d_out, int out_size, void* d_ws, size_t ws_size,
                              hipStream_t stream) {
    const float* logp = (const float*)d_in[0];   // [V]
    const int*   midx = (const int*)d_in[1];     // [T, L]
    float* out = (float*)d_out;                  // [T, V]

    float* ws    = (float*)d_ws;
    float* alpha = ws;                 // 2049 -> pad 2064
    float* beta  = alpha + 2064;       // 2049 -> pad 2064
    float* wf    = beta + 2064;        // 16384
    float* wb    = wf + 16384;         // 16384
    float* Pmf   = wb + 16384;         // 2048
    float* Pmb   = Pmf + 2048;         // 2048
    float* vstf  = Pmb + 2048;         // 264 -> pad 272
    float* vstb  = vstf + 272;         // 264

    scan_fill_kernel<<<dim3(GRID), 256, 0, stream>>>(logp, midx, out, alpha, beta,
                                                     wf, wb, Pmf, Pmb, vstf, vstb);
    scatter_kernel<<<dim3((T * L) / 256), 256, 0, stream>>>(logp, midx, out, alpha, beta);
}

// Round 5
// 310.924 us; speedup vs baseline: 2.5897x; 1.0966x over previous
//
#include <hip/hip_runtime.h>

// UnigramLM forward-backward posterior, T=2048, L=8, V=32000.
// R5 = R4 with compile fix: nontemporal store uses a clang ext_vector float4
//     (HIP's float4 is a struct; the builtin requires a real vector type).
// Log2-domain chunked parallel scan, NCH=64 x K=32, 512-thread scan blocks,
// Pm/vst in LDS; fill = contiguous chunks + nontemporal 16B stores.
//   Kernel A: block 0 = forward scan, block 1 = backward scan,
//             blocks 2.. = 262MB zero-fill (concurrent).
//   Kernel B: scatter exp2(alpha2[t] + w2 + beta2[t+l] - alpha2[T]).

#define NEGV -1e9f
#define LOG2E 1.4426950408889634f
constexpr int T = 2048;
constexpr int L = 8;
constexpr int V = 32000;
constexpr int NCH = 64;   // chunks per scan
constexpr int K = 32;     // steps per chunk (NCH*K == T)
constexpr int BLK = 512;
constexpr int FILLB = 4096;
constexpr int N4 = T * V / 4;          // 16,384,000 16B-vectors
constexpr int CH4 = N4 / FILLB;        // 4000 per fill block (exact)

typedef float vfloat4 __attribute__((ext_vector_type(4)));

__device__ __forceinline__ float hexp2(float x) { return __builtin_amdgcn_exp2f(x); }
__device__ __forceinline__ float hlog2(float x) { return __builtin_amdgcn_logf(x); }

__device__ __forceinline__ float lse8v(float t0, float t1, float t2, float t3,
                                       float t4, float t5, float t6, float t7) {
    // log2-domain logsumexp: m + log2(sum 2^(ti-m))
    float m = fmaxf(fmaxf(fmaxf(t0, t1), fmaxf(t2, t3)),
                    fmaxf(fmaxf(t4, t5), fmaxf(t6, t7)));
    float s = hexp2(t0 - m) + hexp2(t1 - m) + hexp2(t2 - m) + hexp2(t3 - m)
            + hexp2(t4 - m) + hexp2(t5 - m) + hexp2(t6 - m) + hexp2(t7 - m);
    return m + hlog2(s);
}

__global__ __launch_bounds__(BLK) void scan_fill_kernel(
        const float* __restrict__ logp, const int* __restrict__ midx,
        float* __restrict__ out, float* __restrict__ alpha, float* __restrict__ beta,
        float* __restrict__ wf, float* __restrict__ wb) {
    const int tid = threadIdx.x;
    const int bx = blockIdx.x;

    if (bx >= 2) {
        // ---- contiguous zero-fill, nontemporal 16B stores ----
        vfloat4 z = (vfloat4)0.f;
        vfloat4* o4 = (vfloat4*)out;
        const int base4 = (bx - 2) * CH4;
        const int end4 = base4 + CH4;
        for (int i = base4 + tid; i < end4; i += BLK)
            __builtin_nontemporal_store(z, &o4[i]);
        return;
    }

    __shared__ __align__(16) float sPm[NCH * 64];   // 16 KB: per-chunk 8x8 operators
    __shared__ float sVst[(NCH + 1) * 8];           // chunk-boundary states

    // ---- staging: w rows in log2 domain into global scratch (L2-hot) ----
    float* w = (bx == 0) ? wf : wb;
    if (bx == 0) {
        // wf[r][j] = w[r-j][j] * log2e  (NEG if r<j or no match)
        for (int o = tid; o < T * L; o += BLK) {
            int r = o >> 3, j = o & 7, t = r - j;
            float v = NEGV;
            if (t >= 0) { int m = midx[(t << 3) + j]; if (m >= 0) v = logp[m] * LOG2E; }
            wf[o] = v;
        }
        if (tid == 0) alpha[0] = 0.f;
    } else {
        // wb[s][j] = w[T-1-s][j] * log2e
        for (int o = tid; o < T * L; o += BLK) {
            int s = o >> 3, j = o & 7, t = T - 1 - s;
            int m = midx[(t << 3) + j];
            wb[o] = (m >= 0) ? logp[m] * LOG2E : NEGV;
        }
        if (tid == 0) beta[T] = 0.f;
    }
    __syncthreads();

    // ---- phase 1: per-chunk operator composition; thread (c,col) owns column col
    {
        const int c = tid >> 3, col = tid & 7;
        float q[8];
#pragma unroll
        for (int i = 0; i < 8; ++i) q[i] = (i == col) ? 0.f : NEGV;
        const float4* wr4 = (const float4*)(w + c * K * 8);
        float4 c0 = wr4[0], c1 = wr4[1];
        float4 b0 = wr4[2], b1 = wr4[3];
        for (int k = 0; k < K; ++k) {
            float4 a0, a1;
            if (k + 2 < K) { a0 = wr4[(k + 2) * 2]; a1 = wr4[(k + 2) * 2 + 1]; }
            float top = lse8v(c0.x + q[0], c0.y + q[1], c0.z + q[2], c0.w + q[3],
                              c1.x + q[4], c1.y + q[5], c1.z + q[6], c1.w + q[7]);
#pragma unroll
            for (int i = 7; i > 0; --i) q[i] = q[i - 1];
            q[0] = top;
            c0 = b0; c1 = b1; b0 = a0; b1 = a1;
        }
#pragma unroll
        for (int i = 0; i < 8; ++i) sPm[c * 64 + i * 8 + col] = q[i];
    }
    __syncthreads();

    // ---- phase 2: sequential combine across chunks (lanes 0..7 of wave 0, LDS)
    if (tid < 8) {
        const int r = tid;
        float v = (r == 0) ? 0.f : NEGV;
        for (int cc = 0; cc < NCH; ++cc) {
            sVst[cc * 8 + r] = v;
            float4 r0 = *(const float4*)&sPm[cc * 64 + r * 8];
            float4 r1 = *(const float4*)&sPm[cc * 64 + r * 8 + 4];
            float vb0 = __shfl(v, 0, 8), vb1 = __shfl(v, 1, 8);
            float vb2 = __shfl(v, 2, 8), vb3 = __shfl(v, 3, 8);
            float vb4 = __shfl(v, 4, 8), vb5 = __shfl(v, 5, 8);
            float vb6 = __shfl(v, 6, 8), vb7 = __shfl(v, 7, 8);
            v = lse8v(r0.x + vb0, r0.y + vb1, r0.z + vb2, r0.w + vb3,
                      r1.x + vb4, r1.y + vb5, r1.z + vb6, r1.w + vb7);
        }
        sVst[NCH * 8 + r] = v;
    }
    __syncthreads();

    // ---- phase 3: re-run each chunk from its boundary state, emitting values
    if (tid < NCH) {
        const int cc = tid;
        float ab[8];
#pragma unroll
        for (int i = 0; i < 8; ++i) ab[i] = sVst[cc * 8 + i];
        const float4* wr4 = (const float4*)(w + cc * K * 8);
        float4 c0 = wr4[0], c1 = wr4[1];
        float4 b0 = wr4[2], b1 = wr4[3];
        for (int k = 0; k < K; ++k) {
            float4 a0, a1;
            if (k + 2 < K) { a0 = wr4[(k + 2) * 2]; a1 = wr4[(k + 2) * 2 + 1]; }
            float val = lse8v(c0.x + ab[0], c0.y + ab[1], c0.z + ab[2], c0.w + ab[3],
                              c1.x + ab[4], c1.y + ab[5], c1.z + ab[6], c1.w + ab[7]);
            int s = cc * K + k;
            if (bx == 0) alpha[s + 1] = val;
            else         beta[T - 1 - s] = val;
#pragma unroll
            for (int i = 7; i > 0; --i) ab[i] = ab[i - 1];
            ab[0] = val;
            c0 = b0; c1 = b1; b0 = a0; b1 = a1;
        }
    }
}

__global__ __launch_bounds__(256) void scatter_kernel(
        const float* __restrict__ logp, const int* __restrict__ midx,
        float* __restrict__ out, const float* __restrict__ alpha,
        const float* __restrict__ beta) {
    int i = blockIdx.x * blockDim.x + threadIdx.x;
    if (i >= T * L) return;
    int m = midx[i];
    if (m < 0) return;
    int t = i >> 3, j = i & 7;
    int nx = t + j + 1;
    if (nx > T) nx = T;
    float lp2 = alpha[t] + logp[m] * LOG2E + beta[nx] - alpha[T];
    atomicAdd(&out[(size_t)t * V + m], hexp2(lp2));
}

extern "C" void kernel_launch(void* const* d_in, const int* in_sizes, int n_in,
                              void* d_out, int out_size, void* d_ws, size_t ws_size,
                              hipStream_t stream) {
    const float* logp = (const float*)d_in[0];   // [V]
    const int*   midx = (const int*)d_in[1];     // [T, L]
    float* out = (float*)d_out;                  // [T, V]

    float* ws    = (float*)d_ws;
    float* alpha = ws;                 // 2049 -> pad 2064 (log2 domain)
    float* beta  = alpha + 2064;       // 2049 -> pad 2064 (log2 domain)
    float* wf    = beta + 2064;        // 16384
    float* wb    = wf + 16384;         // 16384

    scan_fill_kernel<<<dim3(2 + FILLB), BLK, 0, stream>>>(logp, midx, out, alpha, beta, wf, wb);
    scatter_kernel<<<dim3((T * L) / 256), 256, 0, stream>>>(logp, midx, out, alpha, beta);
}